// Round 1
// baseline (907.937 us; speedup 1.0000x reference)
//
#include <hip/hip_runtime.h>
#include <math.h>

#define NTH 256

// ---------------- wave (64-lane) reductions ----------------
__device__ __forceinline__ float wred_sum(float v) {
#pragma unroll
    for (int o = 32; o > 0; o >>= 1) v += __shfl_down(v, o, 64);
    return v;
}
__device__ __forceinline__ float wred_max(float v) {
#pragma unroll
    for (int o = 32; o > 0; o >>= 1) v = fmaxf(v, __shfl_down(v, o, 64));
    return v;
}
__device__ __forceinline__ float wred_min(float v) {
#pragma unroll
    for (int o = 32; o > 0; o >>= 1) v = fminf(v, __shfl_down(v, o, 64));
    return v;
}
__device__ __forceinline__ int wred_isum(int v) {
#pragma unroll
    for (int o = 32; o > 0; o >>= 1) v += __shfl_down(v, o, 64);
    return v;
}
__device__ __forceinline__ int wred_imin(int v) {
#pragma unroll
    for (int o = 32; o > 0; o >>= 1) v = min(v, __shfl_down(v, o, 64));
    return v;
}
__device__ __forceinline__ int wred_imax(int v) {
#pragma unroll
    for (int o = 32; o > 0; o >>= 1) v = max(v, __shfl_down(v, o, 64));
    return v;
}

// ---------------- block (256-thread, 4-wave) reductions ----------------
// scratch: 4 floats / 4 ints. Leading sync protects WAR on scratch reuse.
__device__ __forceinline__ float bred_sum(float v, float* s4) {
    v = wred_sum(v);
    __syncthreads();
    if ((threadIdx.x & 63) == 0) s4[threadIdx.x >> 6] = v;
    __syncthreads();
    return s4[0] + s4[1] + s4[2] + s4[3];
}
__device__ __forceinline__ float bred_max(float v, float* s4) {
    v = wred_max(v);
    __syncthreads();
    if ((threadIdx.x & 63) == 0) s4[threadIdx.x >> 6] = v;
    __syncthreads();
    return fmaxf(fmaxf(s4[0], s4[1]), fmaxf(s4[2], s4[3]));
}
__device__ __forceinline__ float bred_min(float v, float* s4) {
    v = wred_min(v);
    __syncthreads();
    if ((threadIdx.x & 63) == 0) s4[threadIdx.x >> 6] = v;
    __syncthreads();
    return fminf(fminf(s4[0], s4[1]), fminf(s4[2], s4[3]));
}
__device__ __forceinline__ int bred_isum(int v, int* s4) {
    v = wred_isum(v);
    __syncthreads();
    if ((threadIdx.x & 63) == 0) s4[threadIdx.x >> 6] = v;
    __syncthreads();
    return s4[0] + s4[1] + s4[2] + s4[3];
}
__device__ __forceinline__ int bred_imin(int v, int* s4) {
    v = wred_imin(v);
    __syncthreads();
    if ((threadIdx.x & 63) == 0) s4[threadIdx.x >> 6] = v;
    __syncthreads();
    return min(min(s4[0], s4[1]), min(s4[2], s4[3]));
}
__device__ __forceinline__ int bred_imax(int v, int* s4) {
    v = wred_imax(v);
    __syncthreads();
    if ((threadIdx.x & 63) == 0) s4[threadIdx.x >> 6] = v;
    __syncthreads();
    return max(max(s4[0], s4[1]), max(s4[2], s4[3]));
}

// One block per row. T=2048, 256 threads, 8 elems/thread.
__global__ __launch_bounds__(NTH)
void feat_kernel(const float* __restrict__ gx, float* __restrict__ gout) {
    const int tid = threadIdx.x;
    const int row = blockIdx.x;
    const float* xrow = gx + (size_t)row * 2048;

    // LDS: A,B = FFT ping-pong (A also holds the signal in .x pre-FFT),
    // TW = twiddles. Reduction scratch aliased into B (untouched until FFT);
    // post-FFT reduction scratch aliased into A (dead after last FFT stage).
    __shared__ float2 A[2048];
    __shared__ float2 Bv[2048];
    __shared__ float2 TW[1024];
    float* s4_pre  = (float*)Bv;          // 4 floats
    int*   s4i_pre = ((int*)Bv) + 4;      // 4 ints
    float* s4_post = (float*)A;           // used only after FFT done

    // ---- twiddle table: TW[k] = exp(-2*pi*i*k/2048), k in [0,1024) ----
#pragma unroll
    for (int t = 0; t < 4; ++t) {
        int k = tid + t * 256;
        float ang = (-6.2831853071795864769f / 2048.0f) * (float)k;
        float sv, cv;
        sincosf(ang, &sv, &cv);
        TW[k] = make_float2(cv, sv);
    }

    // ---- load + running max/min/sum ----
    float vmax = -INFINITY, vmin = INFINITY, vsum = 0.0f;
#pragma unroll
    for (int t = 0; t < 8; ++t) {
        int k = tid + t * 256;
        float v = xrow[k];
        A[k] = make_float2(v, 0.0f);
        vmax = fmaxf(vmax, v);
        vmin = fminf(vmin, v);
        vsum += v;
    }
    __syncthreads();

    float mx  = bred_max(vmax, s4_pre);
    float mn  = bred_min(vmin, s4_pre);
    float sum = bred_sum(vsum, s4_pre);
    float mean = sum * (1.0f / 2048.0f);

    // ---- var (ddof=1), two-pass ----
    float ss = 0.0f;
#pragma unroll
    for (int t = 0; t < 8; ++t) {
        int k = tid + t * 256;
        float d = A[k].x - mean;
        ss += d * d;
    }
    float var = bred_sum(ss, s4_pre) * (1.0f / 2047.0f);
    float sd  = sqrtf(var);

    // ---- peaks / valleys (center position p in [1,2046]) ----
    int cp = 0, cvl = 0;
    int minPeak = 1 << 30, minVal = 1 << 30, maxVal = -1;
#pragma unroll
    for (int t = 0; t < 8; ++t) {
        int p = 1 + tid + t * 256;
        if (p <= 2046) {
            float l = A[p - 1].x, m = A[p].x, r = A[p + 1].x;
            bool pk = (l < m) && (m > r);
            bool vl = (l > m) && (m < r);
            cp += pk; cvl += vl;
            if (pk) minPeak = min(minPeak, p);
            if (vl) { minVal = min(minVal, p); maxVal = max(maxVal, p); }
        }
    }
    int n_peaks = bred_isum(cp, s4i_pre);
    int n_vals  = bred_isum(cvl, s4i_pre);
    int p0      = bred_imin(minPeak, s4i_pre);
    int v0      = bred_imin(minVal, s4i_pre);
    int vlast   = bred_imax(maxVal, s4i_pre);

    float PA = 0.0f, A2f = 0.0f, PH = 0.0f, A1f = 0.0f, PWHH = 0.0f;
    if (n_peaks >= 1 && n_vals >= 2) {   // block-uniform branch
        // v1 = first valley strictly after v0
        int minVal2 = 1 << 30;
#pragma unroll
        for (int t = 0; t < 8; ++t) {
            int p = 1 + tid + t * 256;
            if (p <= 2046 && p > v0) {
                float l = A[p - 1].x, m = A[p].x, r = A[p + 1].x;
                if ((l > m) && (m < r)) minVal2 = min(minVal2, p);
            }
        }
        int v1 = bred_imin(minVal2, s4i_pre);

        float sp0 = A[p0].x, sv0 = A[v0].x;
        PH = sp0 - sv0;
        float half = 0.5f * (sp0 + sv0);

        float aPA = 0.0f, aA2 = 0.0f, aA1 = 0.0f;
        int li = 1 << 30, ri = -1;
#pragma unroll
        for (int t = 0; t < 8; ++t) {
            int i = tid + t * 256;
            float si = A[i].x;
            if (i < 2047) {
                float pr = 0.5f * (si + A[i + 1].x);
                if (i >= v0 && i <= vlast - 2) aPA += pr;
                if (i >= p0 && i <= v1 - 2)    aA2 += pr;
                if (i >= v0 && i <= p0 - 2)    aA1 += pr;
            }
            if (si >= half) {
                if (i >= v0 && i < p0)  li = min(li, i);
                if (i > v0 && i <= p0)  ri = max(ri, i);
            }
        }
        PA  = bred_sum(aPA, s4_pre) * (1.0f / 30.0f);
        A2f = bred_sum(aA2, s4_pre) * (1.0f / 30.0f);
        A1f = bred_sum(aA1, s4_pre) * (1.0f / 30.0f);
        int left_i  = bred_imin(li, s4i_pre); if (left_i == (1 << 30)) left_i = v0;
        int right_i = bred_imax(ri, s4i_pre); if (right_i < 0)         right_i = p0;
        PWHH = (float)(right_i - left_i) * (1.0f / 30.0f);
    }

    // ---- 2048-pt complex FFT, Stockham radix-2 autosort ----
    __syncthreads();   // all feature reads of A / scratch-in-B done
    float2* X = A;
    float2* Y = Bv;
    for (int s = 0; s < 11; ++s) {
        const int Ns = 1 << s;
#pragma unroll
        for (int t = 0; t < 4; ++t) {
            int j = tid + t * 256;
            float2 a = X[j];
            float2 b = X[j + 1024];
            int e = (j & (Ns - 1)) << (10 - s);
            float2 w = TW[e];
            float pr = b.x * w.x - b.y * w.y;
            float pi = b.x * w.y + b.y * w.x;
            int d = ((j >> s) << (s + 1)) | (j & (Ns - 1));
            Y[d]      = make_float2(a.x + pr, a.y + pi);
            Y[d + Ns] = make_float2(a.x - pr, a.y - pi);
        }
        __syncthreads();
        float2* tmp = X; X = Y; Y = tmp;
    }
    // 11 stages (odd) -> result now in X == Bv; A is dead scratch.

    float amp_part = 0.0f;
#pragma unroll
    for (int t = 0; t < 8; ++t) {
        int k = tid + t * 256;
        float2 z = X[k];
        amp_part += sqrtf(z.x * z.x + z.y * z.y);
    }
    float mean_amp = bred_sum(amp_part, s4_post) * (1.0f / 2048.0f);

    if (tid == 0) {
        float* o = gout + (size_t)row * 10;
        o[0] = mx;
        o[1] = mx - mn;
        o[2] = var;
        o[3] = sd;
        o[4] = mean_amp;
        o[5] = PA;
        o[6] = A2f;
        o[7] = PH;
        o[8] = A1f;
        o[9] = PWHH;
    }
}

extern "C" void kernel_launch(void* const* d_in, const int* in_sizes, int n_in,
                              void* d_out, int out_size, void* d_ws, size_t ws_size,
                              hipStream_t stream) {
    const float* x = (const float*)d_in[0];
    float* out = (float*)d_out;
    int rows = in_sizes[0] / 2048;   // 32768
    feat_kernel<<<dim3(rows), dim3(NTH), 0, stream>>>(x, out);
}

// Round 2
// 593.203 us; speedup vs baseline: 1.5306x; 1.5306x over previous
//
#include <hip/hip_runtime.h>
#include <math.h>

#define NTH 256
// LDS swizzle: +1 word per 16 -> every FFT stride pattern lands <=2 lanes/bank
#define PADI(i) ((i) + ((i) >> 4))

// ---------------- wave (64-lane) reductions ----------------
__device__ __forceinline__ float wred_sum(float v) {
#pragma unroll
    for (int o = 32; o > 0; o >>= 1) v += __shfl_down(v, o, 64);
    return v;
}
__device__ __forceinline__ float wred_max(float v) {
#pragma unroll
    for (int o = 32; o > 0; o >>= 1) v = fmaxf(v, __shfl_down(v, o, 64));
    return v;
}
__device__ __forceinline__ float wred_min(float v) {
#pragma unroll
    for (int o = 32; o > 0; o >>= 1) v = fminf(v, __shfl_down(v, o, 64));
    return v;
}
__device__ __forceinline__ int wred_isum(int v) {
#pragma unroll
    for (int o = 32; o > 0; o >>= 1) v += __shfl_down(v, o, 64);
    return v;
}
__device__ __forceinline__ int wred_imin(int v) {
#pragma unroll
    for (int o = 32; o > 0; o >>= 1) v = min(v, __shfl_down(v, o, 64));
    return v;
}
__device__ __forceinline__ int wred_imax(int v) {
#pragma unroll
    for (int o = 32; o > 0; o >>= 1) v = max(v, __shfl_down(v, o, 64));
    return v;
}

// ---------------- block (256-thread, 4-wave) reductions ----------------
__device__ __forceinline__ float bred_sum(float v, float* s4) {
    v = wred_sum(v);
    __syncthreads();
    if ((threadIdx.x & 63) == 0) s4[threadIdx.x >> 6] = v;
    __syncthreads();
    return s4[0] + s4[1] + s4[2] + s4[3];
}
__device__ __forceinline__ float bred_max(float v, float* s4) {
    v = wred_max(v);
    __syncthreads();
    if ((threadIdx.x & 63) == 0) s4[threadIdx.x >> 6] = v;
    __syncthreads();
    return fmaxf(fmaxf(s4[0], s4[1]), fmaxf(s4[2], s4[3]));
}
__device__ __forceinline__ float bred_min(float v, float* s4) {
    v = wred_min(v);
    __syncthreads();
    if ((threadIdx.x & 63) == 0) s4[threadIdx.x >> 6] = v;
    __syncthreads();
    return fminf(fminf(s4[0], s4[1]), fminf(s4[2], s4[3]));
}
__device__ __forceinline__ int bred_isum(int v, int* s4) {
    v = wred_isum(v);
    __syncthreads();
    if ((threadIdx.x & 63) == 0) s4[threadIdx.x >> 6] = v;
    __syncthreads();
    return s4[0] + s4[1] + s4[2] + s4[3];
}
__device__ __forceinline__ int bred_imin(int v, int* s4) {
    v = wred_imin(v);
    __syncthreads();
    if ((threadIdx.x & 63) == 0) s4[threadIdx.x >> 6] = v;
    __syncthreads();
    return min(min(s4[0], s4[1]), min(s4[2], s4[3]));
}
__device__ __forceinline__ int bred_imax(int v, int* s4) {
    v = wred_imax(v);
    __syncthreads();
    if ((threadIdx.x & 63) == 0) s4[threadIdx.x >> 6] = v;
    __syncthreads();
    return max(max(s4[0], s4[1]), max(s4[2], s4[3]));
}

// signal accessor: z[n]=(s[2n],s[2n+1]) packed SoA -> s[i]
__device__ __forceinline__ float sval(const float* Zr, const float* Zi, int i) {
    const float* b = (i & 1) ? Zi : Zr;
    return b[PADI(i >> 1)];
}

__global__ void twfill(float2* tw) {
    int k = blockIdx.x * 256 + threadIdx.x;
    if (k < 1024) {
        float sv, cv;
        sincosf((-6.2831853071795864769f / 2048.0f) * (float)k, &sv, &cv);
        tw[k] = make_float2(cv, sv);   // W_2048^k
    }
}

// One block per row. T=2048, 256 threads.
__global__ __launch_bounds__(NTH)
void feat_kernel(const float* __restrict__ gx, float* __restrict__ gout,
                 const float2* __restrict__ gtw) {
    const int tid = threadIdx.x;
    const float* xrow = gx + (size_t)blockIdx.x * 2048;

    // 1024 complex in SoA with swizzle: 1088 floats per array
    __shared__ float Zr0[1088], Zi0[1088], Zr1[1088], Zi1[1088];
    __shared__ float2 TW[1024];      // W_2048^k, k in [0,1024)
    float* s4f    = Zr1;             // pre-FFT float scratch (overwritten by stage 0)
    int*   s4i    = (int*)Zi1;       // pre-FFT int scratch
    float* s4post = Zr0;             // post-FFT scratch (Z0 dead after stage 4)

    // ---- twiddles ----
    if (gtw) {
#pragma unroll
        for (int t = 0; t < 4; ++t) { int k = tid + t * 256; TW[k] = gtw[k]; }
    } else {
#pragma unroll
        for (int t = 0; t < 4; ++t) {
            int k = tid + t * 256;
            float sv, cv;
            sincosf((-6.2831853071795864769f / 2048.0f) * (float)k, &sv, &cv);
            TW[k] = make_float2(cv, sv);
        }
    }

    // ---- load (coalesced float4) + pack z[n]=x[2n]+i x[2n+1] + max/min/sum ----
    const float4* x4 = (const float4*)xrow;
    float vmax = -INFINITY, vmin = INFINITY, vsum = 0.0f;
#pragma unroll
    for (int t = 0; t < 2; ++t) {
        int q = tid + t * 256;          // float4 index; covers z[2q], z[2q+1]
        float4 u = x4[q];
        int n = 2 * q;
        Zr0[PADI(n)]     = u.x; Zi0[PADI(n)]     = u.y;
        Zr0[PADI(n + 1)] = u.z; Zi0[PADI(n + 1)] = u.w;
        vmax = fmaxf(vmax, fmaxf(fmaxf(u.x, u.y), fmaxf(u.z, u.w)));
        vmin = fminf(vmin, fminf(fminf(u.x, u.y), fminf(u.z, u.w)));
        vsum += (u.x + u.y) + (u.z + u.w);
    }
    __syncthreads();

    float mx   = bred_max(vmax, s4f);
    float mn   = bred_min(vmin, s4f);
    float sum  = bred_sum(vsum, s4f);
    float mean = sum * (1.0f / 2048.0f);

    // ---- var (ddof=1) ----
    float ss = 0.0f;
#pragma unroll
    for (int t = 0; t < 8; ++t) {
        int k = tid + t * 256;
        float d = sval(Zr0, Zi0, k) - mean;
        ss += d * d;
    }
    float var = bred_sum(ss, s4f) * (1.0f / 2047.0f);
    float sd  = sqrtf(var);

    // ---- peaks / valleys ----
    int cp = 0, cvl = 0;
    int minPeak = 1 << 30, minVal = 1 << 30, maxVal = -1;
#pragma unroll
    for (int t = 0; t < 8; ++t) {
        int p = 1 + tid + t * 256;
        if (p <= 2046) {
            float l = sval(Zr0, Zi0, p - 1);
            float m = sval(Zr0, Zi0, p);
            float r = sval(Zr0, Zi0, p + 1);
            bool pk = (l < m) && (m > r);
            bool vl = (l > m) && (m < r);
            cp += pk; cvl += vl;
            if (pk) minPeak = min(minPeak, p);
            if (vl) { minVal = min(minVal, p); maxVal = max(maxVal, p); }
        }
    }
    int n_peaks = bred_isum(cp, s4i);
    int n_vals  = bred_isum(cvl, s4i);
    int p0      = bred_imin(minPeak, s4i);
    int v0      = bred_imin(minVal, s4i);
    int vlast   = bred_imax(maxVal, s4i);

    float PA = 0.0f, A2f = 0.0f, PH = 0.0f, A1f = 0.0f, PWHH = 0.0f;
    if (n_peaks >= 1 && n_vals >= 2) {   // block-uniform
        int minVal2 = 1 << 30;
#pragma unroll
        for (int t = 0; t < 8; ++t) {
            int p = 1 + tid + t * 256;
            if (p <= 2046 && p > v0) {
                float l = sval(Zr0, Zi0, p - 1);
                float m = sval(Zr0, Zi0, p);
                float r = sval(Zr0, Zi0, p + 1);
                if ((l > m) && (m < r)) minVal2 = min(minVal2, p);
            }
        }
        int v1 = bred_imin(minVal2, s4i);

        float sp0 = sval(Zr0, Zi0, p0), sv0 = sval(Zr0, Zi0, v0);
        PH = sp0 - sv0;
        float half = 0.5f * (sp0 + sv0);

        float aPA = 0.0f, aA2 = 0.0f, aA1 = 0.0f;
        int li = 1 << 30, ri = -1;
#pragma unroll
        for (int t = 0; t < 8; ++t) {
            int i = tid + t * 256;
            float si = sval(Zr0, Zi0, i);
            if (i < 2047) {
                float pr = 0.5f * (si + sval(Zr0, Zi0, i + 1));
                if (i >= v0 && i <= vlast - 2) aPA += pr;
                if (i >= p0 && i <= v1 - 2)    aA2 += pr;
                if (i >= v0 && i <= p0 - 2)    aA1 += pr;
            }
            if (si >= half) {
                if (i >= v0 && i < p0)  li = min(li, i);
                if (i > v0 && i <= p0)  ri = max(ri, i);
            }
        }
        PA  = bred_sum(aPA, s4f) * (1.0f / 30.0f);
        A2f = bred_sum(aA2, s4f) * (1.0f / 30.0f);
        A1f = bred_sum(aA1, s4f) * (1.0f / 30.0f);
        int left_i  = bred_imin(li, s4i); if (left_i == (1 << 30)) left_i = v0;
        int right_i = bred_imax(ri, s4i); if (right_i < 0)         right_i = p0;
        PWHH = (float)(right_i - left_i) * (1.0f / 30.0f);
    }

    // ---- 1024-pt complex FFT, Stockham radix-4, 5 stages ----
    __syncthreads();   // features done (incl. scratch reads in Z1)
    float *Xr = Zr0, *Xi = Zi0, *Yr = Zr1, *Yi = Zi1;
#pragma unroll
    for (int s = 0; s < 5; ++s) {
        const int Ns = 1 << (2 * s);
        const int j = tid;
        float ar0 = Xr[PADI(j)],       ai0 = Xi[PADI(j)];
        float ar1 = Xr[PADI(j + 256)], ai1 = Xi[PADI(j + 256)];
        float ar2 = Xr[PADI(j + 512)], ai2 = Xi[PADI(j + 512)];
        float ar3 = Xr[PADI(j + 768)], ai3 = Xi[PADI(j + 768)];
        const int e = (j & (Ns - 1)) * (256 >> (2 * s));   // e < 256
        float2 w1 = TW[2 * e];                              // W_1024^e
        float w2r = w1.x * w1.x - w1.y * w1.y, w2i = 2.0f * w1.x * w1.y;
        float w3r = w2r * w1.x - w2i * w1.y,   w3i = w2r * w1.y + w2i * w1.x;
        float b1r = ar1 * w1.x - ai1 * w1.y,   b1i = ar1 * w1.y + ai1 * w1.x;
        float b2r = ar2 * w2r  - ai2 * w2i,    b2i = ar2 * w2i  + ai2 * w2r;
        float b3r = ar3 * w3r  - ai3 * w3i,    b3i = ar3 * w3i  + ai3 * w3r;
        float t0r = ar0 + b2r, t0i = ai0 + b2i;
        float t1r = b1r + b3r, t1i = b1i + b3i;
        float t2r = ar0 - b2r, t2i = ai0 - b2i;
        float t3r = b1r - b3r, t3i = b1i - b3i;
        const int d = ((j >> (2 * s)) << (2 * s + 2)) | (j & (Ns - 1));
        Yr[PADI(d)]          = t0r + t1r;  Yi[PADI(d)]          = t0i + t1i;
        Yr[PADI(d + Ns)]     = t2r + t3i;  Yi[PADI(d + Ns)]     = t2i - t3r;  // t2 - i*t3
        Yr[PADI(d + 2 * Ns)] = t0r - t1r;  Yi[PADI(d + 2 * Ns)] = t0i - t1i;
        Yr[PADI(d + 3 * Ns)] = t2r - t3i;  Yi[PADI(d + 3 * Ns)] = t2i + t3r;  // t2 + i*t3
        __syncthreads();
        float* tr;
        tr = Xr; Xr = Yr; Yr = tr;
        tr = Xi; Xi = Yi; Yi = tr;
    }
    // result Z = FFT_1024(z) now in Xr/Xi (== Zr1/Zi1); Z0 is dead scratch

    // ---- real-split: X[k]=E+W*O, X[k+1024]=E-W*O; sum |X| over all 2048 bins ----
    float amp = 0.0f;
#pragma unroll
    for (int t = 0; t < 4; ++t) {
        int k  = tid + t * 256;
        int km = (1024 - k) & 1023;
        float zr = Xr[PADI(k)],  zi = Xi[PADI(k)];
        float mr = Xr[PADI(km)], mi = Xi[PADI(km)];
        float Fer = 0.5f * (zr + mr), Fei = 0.5f * (zi - mi);
        float For = 0.5f * (zi + mi), Foi = 0.5f * (mr - zr);
        float2 w = TW[k];                                   // W_2048^k
        float pr = For * w.x - Foi * w.y, pi = For * w.y + Foi * w.x;
        float x1r = Fer + pr, x1i = Fei + pi;
        float x2r = Fer - pr, x2i = Fei - pi;
        amp += sqrtf(x1r * x1r + x1i * x1i) + sqrtf(x2r * x2r + x2i * x2i);
    }
    float mean_amp = bred_sum(amp, s4post) * (1.0f / 2048.0f);

    if (tid == 0) {
        float* o = gout + (size_t)blockIdx.x * 10;
        o[0] = mx;
        o[1] = mx - mn;
        o[2] = var;
        o[3] = sd;
        o[4] = mean_amp;
        o[5] = PA;
        o[6] = A2f;
        o[7] = PH;
        o[8] = A1f;
        o[9] = PWHH;
    }
}

extern "C" void kernel_launch(void* const* d_in, const int* in_sizes, int n_in,
                              void* d_out, int out_size, void* d_ws, size_t ws_size,
                              hipStream_t stream) {
    const float* x = (const float*)d_in[0];
    float* out = (float*)d_out;
    int rows = in_sizes[0] / 2048;   // 32768
    float2* gtw = nullptr;
    if (ws_size >= 1024 * sizeof(float2)) {
        gtw = (float2*)d_ws;
        twfill<<<dim3(4), dim3(256), 0, stream>>>(gtw);
    }
    feat_kernel<<<dim3(rows), dim3(NTH), 0, stream>>>(x, out, gtw);
}

// Round 3
// 529.770 us; speedup vs baseline: 1.7138x; 1.1197x over previous
//
#include <hip/hip_runtime.h>
#include <math.h>

#define NTH 256
// LDS word-index swizzle: +1 word per 16 -> power-of-2 strides land <=2 lanes/bank
#define PADI(i) ((i) + ((i) >> 4))

__global__ void twfill(float* twc, float* tws) {
    int k = blockIdx.x * 256 + threadIdx.x;
    if (k < 1024) {
        float sv, cv;
        sincosf((-6.2831853071795864769f / 2048.0f) * (float)k, &sv, &cv);
        twc[k] = cv;   // W_2048^k = (cos, -sin) stored as (cv, sv) with sv = sin(-theta)
        tws[k] = sv;
    }
}

// One block per row. T=2048, 256 threads, 8 contiguous elems/thread in registers.
__global__ __launch_bounds__(NTH, 8)
void feat_kernel(const float* __restrict__ gx, float* __restrict__ gout,
                 const float* __restrict__ gtwc, const float* __restrict__ gtws) {
    const int tid  = threadIdx.x;
    const int wv   = tid >> 6;
    const int lane = tid & 63;
    const float* xrow = gx + (size_t)blockIdx.x * 2048;

    __shared__ float Zr[1088], Zi[1088];     // 1024-pt complex, in-place FFT
    __shared__ float TWc[1088], TWs[1088];   // W_2048^k SoA, swizzled
    __shared__ float edgeF[256], edgeL[256]; // per-thread first/last element
    __shared__ float sf[12];
    __shared__ int   si[20];
    __shared__ float sc[2];                  // s[p0], s[v0]

    // ---- twiddles ----
    if (gtwc) {
#pragma unroll
        for (int t = 0; t < 4; ++t) {
            int k = tid + t * 256;
            TWc[PADI(k)] = gtwc[k];
            TWs[PADI(k)] = gtws[k];
        }
    } else {
#pragma unroll
        for (int t = 0; t < 4; ++t) {
            int k = tid + t * 256;
            float sv, cv;
            sincosf((-6.2831853071795864769f / 2048.0f) * (float)k, &sv, &cv);
            TWc[PADI(k)] = cv;
            TWs[PADI(k)] = sv;
        }
    }

    // ---- load 8 contiguous elems into registers (coalesced float4 pairs) ----
    const float4* x4 = (const float4*)xrow;
    float4 u0 = x4[2 * tid], u1 = x4[2 * tid + 1];
    float r[8] = {u0.x, u0.y, u0.z, u0.w, u1.x, u1.y, u1.z, u1.w};

    // pack z[n] = x[2n] + i*x[2n+1]; thread owns z[4t..4t+3]
#pragma unroll
    for (int c = 0; c < 4; ++c) {
        Zr[PADI(4 * tid + c)] = r[2 * c];
        Zi[PADI(4 * tid + c)] = r[2 * c + 1];
    }
    edgeF[tid] = r[0];
    edgeL[tid] = r[7];

    // ---- max / min / sum (combined block reduction) ----
    float vmax = r[0], vmin = r[0], vsum = r[0];
#pragma unroll
    for (int e = 1; e < 8; ++e) {
        vmax = fmaxf(vmax, r[e]); vmin = fminf(vmin, r[e]); vsum += r[e];
    }
#pragma unroll
    for (int o = 32; o > 0; o >>= 1) {
        vmax = fmaxf(vmax, __shfl_down(vmax, o, 64));
        vmin = fminf(vmin, __shfl_down(vmin, o, 64));
        vsum += __shfl_down(vsum, o, 64);
    }
    __syncthreads();
    if (lane == 0) { sf[wv] = vmax; sf[4 + wv] = vmin; sf[8 + wv] = vsum; }
    __syncthreads();
    float mx   = fmaxf(fmaxf(sf[0], sf[1]), fmaxf(sf[2], sf[3]));
    float mn   = fminf(fminf(sf[4], sf[5]), fminf(sf[6], sf[7]));
    float mean = (sf[8] + sf[9] + sf[10] + sf[11]) * (1.0f / 2048.0f);

    // ---- var (ddof=1) ----
    float ss = 0.0f;
#pragma unroll
    for (int e = 0; e < 8; ++e) { float d = r[e] - mean; ss += d * d; }
#pragma unroll
    for (int o = 32; o > 0; o >>= 1) ss += __shfl_down(ss, o, 64);
    __syncthreads();
    if (lane == 0) sf[wv] = ss;
    __syncthreads();
    float var = (sf[0] + sf[1] + sf[2] + sf[3]) * (1.0f / 2047.0f);
    float sd  = sqrtf(var);

    // ---- peaks / valleys from registers (centers p in [1,2046]) ----
    float lN = (tid > 0)   ? edgeL[tid - 1] : 0.0f;
    float rN = (tid < 255) ? edgeF[tid + 1] : 0.0f;
    int pmask = 0, vmask = 0;
#pragma unroll
    for (int e = 0; e < 8; ++e) {
        int p = 8 * tid + e;
        float l = (e == 0) ? lN : r[e - 1];
        float m = r[e];
        float rt = (e == 7) ? rN : r[e + 1];
        bool ok = (p >= 1) && (p <= 2046);
        pmask |= (int)(ok && (l < m) && (m > rt)) << e;
        vmask |= (int)(ok && (l > m) && (m < rt)) << e;
    }
    int cp  = __popc(pmask), cvl = __popc(vmask);
    int mp  = pmask ? 8 * tid + (__ffs(pmask) - 1) : (1 << 30);
    int mv  = vmask ? 8 * tid + (__ffs(vmask) - 1) : (1 << 30);
    int Mv  = vmask ? 8 * tid + (31 - __clz(vmask)) : -1;
#pragma unroll
    for (int o = 32; o > 0; o >>= 1) {
        cp += __shfl_down(cp, o, 64);
        cvl += __shfl_down(cvl, o, 64);
        mp = min(mp, __shfl_down(mp, o, 64));
        mv = min(mv, __shfl_down(mv, o, 64));
        Mv = max(Mv, __shfl_down(Mv, o, 64));
    }
    __syncthreads();
    if (lane == 0) {
        si[wv] = cp; si[4 + wv] = cvl; si[8 + wv] = mp; si[12 + wv] = mv; si[16 + wv] = Mv;
    }
    __syncthreads();
    int n_peaks = si[0] + si[1] + si[2] + si[3];
    int n_vals  = si[4] + si[5] + si[6] + si[7];
    int p0      = min(min(si[8], si[9]), min(si[10], si[11]));
    int v0      = min(min(si[12], si[13]), min(si[14], si[15]));
    int vlast   = max(max(si[16], si[17]), max(si[18], si[19]));

    float PA = 0.0f, A2f = 0.0f, PH = 0.0f, A1f = 0.0f, PWHH = 0.0f;
    if (n_peaks >= 1 && n_vals >= 2) {   // block-uniform branch
        // v1 = first valley strictly after v0 (register mask math)
        int lo = v0 - 8 * tid;
        int sel = (lo < 0) ? 0xFF : ((lo >= 7) ? 0 : ((0xFF << (lo + 1)) & 0xFF));
        int m2 = vmask & sel;
        int mv2 = m2 ? 8 * tid + (__ffs(m2) - 1) : (1 << 30);
#pragma unroll
        for (int o = 32; o > 0; o >>= 1) mv2 = min(mv2, __shfl_down(mv2, o, 64));
        __syncthreads();
        if (lane == 0) si[wv] = mv2;
        __syncthreads();
        int v1 = min(min(si[0], si[1]), min(si[2], si[3]));

        // s[p0], s[v0] via tiny scratch
        if ((p0 >> 3) == tid) sc[0] = r[p0 & 7];
        if ((v0 >> 3) == tid) sc[1] = r[v0 & 7];
        __syncthreads();
        float sp0 = sc[0], sv0 = sc[1];
        PH = sp0 - sv0;
        float half = 0.5f * (sp0 + sv0);

        float aPA = 0.0f, aA2 = 0.0f, aA1 = 0.0f;
        int li = 1 << 30, ri = -1;
#pragma unroll
        for (int e = 0; e < 8; ++e) {
            int i = 8 * tid + e;
            float siv = r[e];
            if (i < 2047) {
                float nx = (e == 7) ? rN : r[e + 1];
                float pr = 0.5f * (siv + nx);
                if (i >= v0 && i <= vlast - 2) aPA += pr;
                if (i >= p0 && i <= v1 - 2)    aA2 += pr;
                if (i >= v0 && i <= p0 - 2)    aA1 += pr;
            }
            if (siv >= half) {
                if (i >= v0 && i < p0)  li = min(li, i);
                if (i > v0 && i <= p0)  ri = max(ri, i);
            }
        }
#pragma unroll
        for (int o = 32; o > 0; o >>= 1) {
            aPA += __shfl_down(aPA, o, 64);
            aA2 += __shfl_down(aA2, o, 64);
            aA1 += __shfl_down(aA1, o, 64);
            li = min(li, __shfl_down(li, o, 64));
            ri = max(ri, __shfl_down(ri, o, 64));
        }
        __syncthreads();
        if (lane == 0) {
            sf[wv] = aPA; sf[4 + wv] = aA2; sf[8 + wv] = aA1;
            si[wv] = li;  si[4 + wv] = ri;
        }
        __syncthreads();
        PA  = (sf[0] + sf[1] + sf[2] + sf[3]) * (1.0f / 30.0f);
        A2f = (sf[4] + sf[5] + sf[6] + sf[7]) * (1.0f / 30.0f);
        A1f = (sf[8] + sf[9] + sf[10] + sf[11]) * (1.0f / 30.0f);
        int left_i  = min(min(si[0], si[1]), min(si[2], si[3]));
        int right_i = max(max(si[4], si[5]), max(si[6], si[7]));
        if (left_i == (1 << 30)) left_i = v0;
        if (right_i < 0)         right_i = p0;
        PWHH = (float)(right_i - left_i) * (1.0f / 30.0f);
    }

    // ---- 1024-pt complex FFT, Stockham radix-4, in-place read-sync-write ----
    __syncthreads();
#pragma unroll
    for (int s = 0; s < 5; ++s) {
        const int Ns = 1 << (2 * s);
        const int j = tid;
        float ar0 = Zr[PADI(j)],       ai0 = Zi[PADI(j)];
        float ar1 = Zr[PADI(j + 256)], ai1 = Zi[PADI(j + 256)];
        float ar2 = Zr[PADI(j + 512)], ai2 = Zi[PADI(j + 512)];
        float ar3 = Zr[PADI(j + 768)], ai3 = Zi[PADI(j + 768)];
        float w1x, w1y;
        if (s == 0) { w1x = 1.0f; w1y = 0.0f; }
        else {
            const int e = (j & (Ns - 1)) * (256 >> (2 * s));   // e < 256
            w1x = TWc[PADI(2 * e)];                             // W_1024^e
            w1y = TWs[PADI(2 * e)];
        }
        float w2r = w1x * w1x - w1y * w1y, w2i = 2.0f * w1x * w1y;
        float w3r = w2r * w1x - w2i * w1y, w3i = w2r * w1y + w2i * w1x;
        float b1r = ar1 * w1x - ai1 * w1y, b1i = ar1 * w1y + ai1 * w1x;
        float b2r = ar2 * w2r - ai2 * w2i, b2i = ar2 * w2i + ai2 * w2r;
        float b3r = ar3 * w3r - ai3 * w3i, b3i = ar3 * w3i + ai3 * w3r;
        float t0r = ar0 + b2r, t0i = ai0 + b2i;
        float t1r = b1r + b3r, t1i = b1i + b3i;
        float t2r = ar0 - b2r, t2i = ai0 - b2i;
        float t3r = b1r - b3r, t3i = b1i - b3i;
        const int d = ((j >> (2 * s)) << (2 * s + 2)) | (j & (Ns - 1));
        __syncthreads();   // all reads done before any writes
        Zr[PADI(d)]          = t0r + t1r;  Zi[PADI(d)]          = t0i + t1i;
        Zr[PADI(d + Ns)]     = t2r + t3i;  Zi[PADI(d + Ns)]     = t2i - t3r;  // t2 - i*t3
        Zr[PADI(d + 2 * Ns)] = t0r - t1r;  Zi[PADI(d + 2 * Ns)] = t0i - t1i;
        Zr[PADI(d + 3 * Ns)] = t2r - t3i;  Zi[PADI(d + 3 * Ns)] = t2i + t3r;  // t2 + i*t3
        __syncthreads();
    }

    // ---- real-split + sum |X| over 2048 bins ----
    float amp = 0.0f;
#pragma unroll
    for (int t = 0; t < 4; ++t) {
        int k  = tid + t * 256;
        int km = (1024 - k) & 1023;
        float zr = Zr[PADI(k)],  zi = Zi[PADI(k)];
        float mr = Zr[PADI(km)], mi = Zi[PADI(km)];
        float Fer = 0.5f * (zr + mr), Fei = 0.5f * (zi - mi);
        float For = 0.5f * (zi + mi), Foi = 0.5f * (mr - zr);
        float wx = TWc[PADI(k)], wy = TWs[PADI(k)];          // W_2048^k
        float pr = For * wx - Foi * wy, pi = For * wy + Foi * wx;
        float x1r = Fer + pr, x1i = Fei + pi;
        float x2r = Fer - pr, x2i = Fei - pi;
        amp += sqrtf(x1r * x1r + x1i * x1i) + sqrtf(x2r * x2r + x2i * x2i);
    }
#pragma unroll
    for (int o = 32; o > 0; o >>= 1) amp += __shfl_down(amp, o, 64);
    __syncthreads();
    if (lane == 0) sf[wv] = amp;
    __syncthreads();
    float mean_amp = (sf[0] + sf[1] + sf[2] + sf[3]) * (1.0f / 2048.0f);

    if (tid == 0) {
        float* o = gout + (size_t)blockIdx.x * 10;
        o[0] = mx;
        o[1] = mx - mn;
        o[2] = var;
        o[3] = sd;
        o[4] = mean_amp;
        o[5] = PA;
        o[6] = A2f;
        o[7] = PH;
        o[8] = A1f;
        o[9] = PWHH;
    }
}

extern "C" void kernel_launch(void* const* d_in, const int* in_sizes, int n_in,
                              void* d_out, int out_size, void* d_ws, size_t ws_size,
                              hipStream_t stream) {
    const float* x = (const float*)d_in[0];
    float* out = (float*)d_out;
    int rows = in_sizes[0] / 2048;   // 32768
    float* twc = nullptr;
    float* tws = nullptr;
    if (ws_size >= 2048 * sizeof(float)) {
        twc = (float*)d_ws;
        tws = twc + 1024;
        twfill<<<dim3(4), dim3(256), 0, stream>>>(twc, tws);
    }
    feat_kernel<<<dim3(rows), dim3(NTH), 0, stream>>>(x, out, twc, tws);
}

// Round 4
// 396.045 us; speedup vs baseline: 2.2925x; 1.3377x over previous
//
#include <hip/hip_runtime.h>
#include <math.h>

#define NTH 256
// pad one word per 64 -> all FFT access patterns land <=2-way banked (hand-checked)
#define PAD64(i) ((i) + ((i) >> 6))

// (vr,vi) *= (c,s)
#define CMUL(vr, vi, c, s) { float _tr = (vr)*(c) - (vi)*(s); (vi) = (vr)*(s) + (vi)*(c); (vr) = _tr; }

// in-place FFT-4, natural order, W4 = -i
#define FFT4(r0,i0,r1,i1,r2,i2,r3,i3) {                     \
    float _acr=(r0)+(r2), _aci=(i0)+(i2);                   \
    float _scr=(r0)-(r2), _sci=(i0)-(i2);                   \
    float _bdr=(r1)+(r3), _bdi=(i1)+(i3);                   \
    float _sdr=(r1)-(r3), _sdi=(i1)-(i3);                   \
    (r0)=_acr+_bdr; (i0)=_aci+_bdi;                         \
    (r1)=_scr+_sdi; (i1)=_sci-_sdr;                         \
    (r2)=_acr-_bdr; (i2)=_aci-_bdi;                         \
    (r3)=_scr-_sdi; (i3)=_sci+_sdr; }

// FFT-16, natural input x[n]. OUTPUT DIGIT-SWAPPED: slot (4s+g) holds Y[s+4g].
__device__ __forceinline__ void fft16(float* xr, float* xi) {
    const float C1 = 0.92387953251128675613f;   // cos(pi/8)
    const float S1 = 0.38268343236508977172f;   // sin(pi/8)
    const float R2 = 0.70710678118654752440f;
    // stage 1: FFT4 over t of x[4t+q]; slot 4s+q <- F_q[s]
#pragma unroll
    for (int q = 0; q < 4; ++q)
        FFT4(xr[q], xi[q], xr[4+q], xi[4+q], xr[8+q], xi[8+q], xr[12+q], xi[12+q]);
    // stage 2: slot 4s+q *= W16^(q*s)
    CMUL(xr[5],  xi[5],   C1, -S1);                              // W^1
    CMUL(xr[9],  xi[9],   R2, -R2);                              // W^2
    CMUL(xr[13], xi[13],  S1, -C1);                              // W^3
    CMUL(xr[6],  xi[6],   R2, -R2);                              // W^2
    { float t = xr[10]; xr[10] = xi[10]; xi[10] = -t; }          // W^4 = -i
    CMUL(xr[14], xi[14], -R2, -R2);                              // W^6
    CMUL(xr[7],  xi[7],   S1, -C1);                              // W^3
    CMUL(xr[11], xi[11], -R2, -R2);                              // W^6
    CMUL(xr[15], xi[15], -C1,  S1);                              // W^9
    // stage 3: FFT4 over q at slots 4s+q; slot 4s+g <- Y[s+4g]
#pragma unroll
    for (int s = 0; s < 4; ++s)
        FFT4(xr[4*s], xi[4*s], xr[4*s+1], xi[4*s+1], xr[4*s+2], xi[4*s+2], xr[4*s+3], xi[4*s+3]);
}

// One WAVE per row (4 rows / 256-thread block). T=2048. No __syncthreads anywhere:
// all LDS hazards are same-wave (DS ops execute in issue order per wave).
__global__ __launch_bounds__(NTH, 4)
void feat_kernel(const float* __restrict__ gx, float* __restrict__ gout) {
    const int tid = threadIdx.x;
    const int wv  = tid >> 6;
    const int ln  = tid & 63;
    const int row = blockIdx.x * 4 + wv;
    const float* xrow = gx + (size_t)row * 2048;

    __shared__ float ZRs[4][1040], ZIs[4][1040];
    float* Zr = ZRs[wv];
    float* Zi = ZIs[wv];

    // ---- coalesced load; pack z[n]=x[2n]+i*x[2n+1] into LDS ----
    const float4* x4 = (const float4*)xrow;
#pragma unroll
    for (int t = 0; t < 8; ++t) {
        float4 u = x4[ln + 64 * t];
        int c = 2 * (ln + 64 * t);        // even; PAD64(c+1)==PAD64(c)+1
        int a = PAD64(c);
        Zr[a]     = u.x; Zi[a]     = u.y;
        Zr[a + 1] = u.z; Zi[a + 1] = u.w;
    }

    // ---- contiguous 32 samples into regs: s[32*ln + m] ----
    float r[32];
    {
        int base = PAD64(16 * ln);        // +j contiguous for j<16
#pragma unroll
        for (int j = 0; j < 16; ++j) {
            r[2*j]   = Zr[base + j];
            r[2*j+1] = Zi[base + j];
        }
    }

    // ---- max / min / mean (wave butterfly reductions) ----
    float vmax = r[0], vmin = r[0], vsum = r[0];
#pragma unroll
    for (int e = 1; e < 32; ++e) {
        vmax = fmaxf(vmax, r[e]); vmin = fminf(vmin, r[e]); vsum += r[e];
    }
#pragma unroll
    for (int o = 1; o < 64; o <<= 1) {
        vmax = fmaxf(vmax, __shfl_xor(vmax, o, 64));
        vmin = fminf(vmin, __shfl_xor(vmin, o, 64));
        vsum += __shfl_xor(vsum, o, 64);
    }
    float mx = vmax, mn = vmin, mean = vsum * (1.0f / 2048.0f);

    // ---- var (ddof=1) ----
    float ss = 0.0f;
#pragma unroll
    for (int e = 0; e < 32; ++e) { float d = r[e] - mean; ss += d * d; }
#pragma unroll
    for (int o = 1; o < 64; o <<= 1) ss += __shfl_xor(ss, o, 64);
    float var = ss * (1.0f / 2047.0f);
    float sd  = sqrtf(var);

    // ---- peaks / valleys: 32-bit masks per lane ----
    float lN = __shfl_up(r[31], 1, 64);     // lane-1's last elem (lane0: dead, p=0 masked)
    float rN = __shfl_down(r[0], 1, 64);    // lane+1's first elem (lane63: dead, p=2047 masked)
    unsigned pm = 0, vm = 0;
#pragma unroll
    for (int m = 0; m < 32; ++m) {
        int p = 32 * ln + m;
        float l  = (m == 0)  ? lN : r[m - 1];
        float mm = r[m];
        float rt = (m == 31) ? rN : r[m + 1];
        bool ok = (p >= 1) && (p <= 2046);
        pm |= (unsigned)(ok && (l < mm) && (mm > rt)) << m;
        vm |= (unsigned)(ok && (l > mm) && (mm < rt)) << m;
    }
    int cp = __popc(pm), cv = __popc(vm);
    int mp = pm ? 32 * ln + __ffs(pm) - 1 : (1 << 30);
    int mv = vm ? 32 * ln + __ffs(vm) - 1 : (1 << 30);
    int Mv = vm ? 32 * ln + 31 - __clz(vm) : -1;
#pragma unroll
    for (int o = 1; o < 64; o <<= 1) {
        cp += __shfl_xor(cp, o, 64);
        cv += __shfl_xor(cv, o, 64);
        mp = min(mp, __shfl_xor(mp, o, 64));
        mv = min(mv, __shfl_xor(mv, o, 64));
        Mv = max(Mv, __shfl_xor(Mv, o, 64));
    }
    const int n_peaks = cp, n_vals = cv, p0 = mp, v0 = mv, vlast = Mv;

    float PA = 0.0f, A2f = 0.0f, PH = 0.0f, A1f = 0.0f, PW = 0.0f;
    if (n_peaks >= 1 && n_vals >= 2) {     // wave-uniform
        // v1 = first valley strictly after v0
        int lo = v0 - 32 * ln;
        unsigned sel = (lo < 0) ? 0xFFFFFFFFu : ((lo >= 31) ? 0u : (0xFFFFFFFFu << (lo + 1)));
        unsigned m2 = vm & sel;
        int mv2 = m2 ? 32 * ln + __ffs(m2) - 1 : (1 << 30);
#pragma unroll
        for (int o = 1; o < 64; o <<= 1) mv2 = min(mv2, __shfl_xor(mv2, o, 64));
        int v1 = mv2;

        float sp0 = (p0 & 1) ? Zi[PAD64(p0 >> 1)] : Zr[PAD64(p0 >> 1)];  // broadcast read
        float sv0 = (v0 & 1) ? Zi[PAD64(v0 >> 1)] : Zr[PAD64(v0 >> 1)];
        PH = sp0 - sv0;
        float half = 0.5f * (sp0 + sv0);

        float aPA = 0.0f, aA2 = 0.0f, aA1 = 0.0f;
        int li = 1 << 30, ri = -1;
#pragma unroll
        for (int m = 0; m < 32; ++m) {
            int i = 32 * ln + m;
            float si = r[m];
            if (i < 2047) {
                float nx = (m == 31) ? rN : r[m + 1];
                float pr = 0.5f * (si + nx);
                if (i >= v0 && i <= vlast - 2) aPA += pr;
                if (i >= p0 && i <= v1 - 2)    aA2 += pr;
                if (i >= v0 && i <= p0 - 2)    aA1 += pr;
            }
            if (si >= half) {
                if (i >= v0 && i < p0)  li = min(li, i);
                if (i > v0 && i <= p0)  ri = max(ri, i);
            }
        }
#pragma unroll
        for (int o = 1; o < 64; o <<= 1) {
            aPA += __shfl_xor(aPA, o, 64);
            aA2 += __shfl_xor(aA2, o, 64);
            aA1 += __shfl_xor(aA1, o, 64);
            li = min(li, __shfl_xor(li, o, 64));
            ri = max(ri, __shfl_xor(ri, o, 64));
        }
        PA  = aPA * (1.0f / 30.0f);
        A2f = aA2 * (1.0f / 30.0f);
        A1f = aA1 * (1.0f / 30.0f);
        if (li == (1 << 30)) li = v0;
        if (ri < 0)          ri = p0;
        PW = (float)(ri - li) * (1.0f / 30.0f);
    }

    // ================= FFT-1024: Z[k2+16k1] via 16 x (16 x 4) =================
    // step A: per-lane FFT-16 over n2 of z[ln + 64*n2]
    float ar[16], ai[16];
#pragma unroll
    for (int n2 = 0; n2 < 16; ++n2) {
        ar[n2] = Zr[ln + 65 * n2];           // PAD64(ln+64*n2) = ln + 65*n2
        ai[n2] = Zi[ln + 65 * n2];
    }
    fft16(ar, ai);
    // step B: *= W1024^(ln*k2); write slot L = 16*ln + k2  (slot idx 4s+g -> k2 = s+4g)
    {
        int wbase = PAD64(16 * ln);
        float fl = (float)ln;
#pragma unroll
        for (int idx = 0; idx < 16; ++idx) {
            int k2 = (idx >> 2) + 4 * (idx & 3);
            if (k2 > 0) {
                float ang = fl * (float)k2 * (-6.2831853071795864769e0f / 1024.0f);
                float c = __cosf(ang), s = __sinf(ang);
                CMUL(ar[idx], ai[idx], c, s);
            }
            Zr[wbase + k2] = ar[idx];
            Zi[wbase + k2] = ai[idx];
        }
    }
    // step C: lane' = alpha + 4*k2 gathers v[alpha+4*beta] = slot 16*alpha + 64*beta + k2
    const int al  = ln & 3;
    const int k2r = ln >> 2;
    {
        int base = 16 * al + k2r;            // <64, PAD64 = id; +65*beta
#pragma unroll
        for (int b = 0; b < 16; ++b) {
            ar[b] = Zr[base + 65 * b];
            ai[b] = Zi[base + 65 * b];
        }
    }
    fft16(ar, ai);                           // slot 4s+g holds u[j], j = s+4g
    // C2: *= W64^(al*j)
    {
        float fa = (float)al;
#pragma unroll
        for (int idx = 0; idx < 16; ++idx) {
            int j = (idx >> 2) + 4 * (idx & 3);
            if (j > 0) {
                float ang = fa * (float)j * (-6.2831853071795864769e0f / 64.0f);
                float c = __cosf(ang), s = __sinf(ang);
                CMUL(ar[idx], ai[idx], c, s);
            }
        }
    }
    // C3: FFT-4 over alpha (cross-lane, 2 shfl_xor stages); lane al ends with g = bitrev2(al)
    // final: Z[K], K = k2 + 16*j + 256*g ; addr = (k2 + 260*g) + 16*j + (j>>2)
    {
        const bool hi = (al & 2) != 0;
        const bool b0 = (al & 1) != 0;
        const int g = ((al & 1) << 1) | (al >> 1);
        int fbase = k2r + 260 * g;
#pragma unroll
        for (int idx = 0; idx < 16; ++idx) {
            int j = (idx >> 2) + 4 * (idx & 3);
            float tr = __shfl_xor(ar[idx], 2, 64);
            float ti = __shfl_xor(ai[idx], 2, 64);
            float vr = hi ? (tr - ar[idx]) : (ar[idx] + tr);
            float vi = hi ? (ti - ai[idx]) : (ai[idx] + ti);
            float sr = __shfl_xor(vr, 1, 64);
            float si = __shfl_xor(vi, 1, 64);
            float Xr, Xi;
            if (!b0) { Xr = hi ? (vr + si) : (vr + sr); Xi = hi ? (vi - sr) : (vi + si); }
            else     { Xr = hi ? (sr - vi) : (sr - vr); Xi = hi ? (si + vr) : (si - vi); }
            Zr[fbase + 16 * j + (j >> 2)] = Xr;
            Zi[fbase + 16 * j + (j >> 2)] = Xi;
        }
    }

    // ---- real-split: sum |X[k]| over all 2048 bins via k=0..512 w/ weights ----
    float amp = 0.0f;
#pragma unroll
    for (int t = 0; t < 9; ++t) {
        int k = ln + 64 * t;
        if (k <= 512) {
            int m = (1024 - k) & 1023;
            float zr = Zr[ln + 65 * t], zi = Zi[ln + 65 * t];   // PAD64(k)
            int ma = PAD64(m);
            float mr = Zr[ma], mi = Zi[ma];
            float Er = 0.5f * (zr + mr), Ei = 0.5f * (zi - mi);
            float Or = 0.5f * (zi + mi), Oi = 0.5f * (mr - zr);
            float ang = (float)k * (-3.14159265358979323846f / 1024.0f);  // W2048^k
            float c = __cosf(ang), s = __sinf(ang);
            float Pr = Or * c - Oi * s, Pi = Or * s + Oi * c;
            float x1r = Er + Pr, x1i = Ei + Pi;
            float x2r = Er - Pr, x2i = Ei - Pi;
            float w = (k == 0 || k == 512) ? 1.0f : 2.0f;
            amp += w * (__builtin_amdgcn_sqrtf(x1r * x1r + x1i * x1i) +
                        __builtin_amdgcn_sqrtf(x2r * x2r + x2i * x2i));
        }
    }
#pragma unroll
    for (int o = 1; o < 64; o <<= 1) amp += __shfl_xor(amp, o, 64);
    float mean_amp = amp * (1.0f / 2048.0f);

    if (ln == 0) {
        float* o = gout + (size_t)row * 10;
        o[0] = mx;
        o[1] = mx - mn;
        o[2] = var;
        o[3] = sd;
        o[4] = mean_amp;
        o[5] = PA;
        o[6] = A2f;
        o[7] = PH;
        o[8] = A1f;
        o[9] = PW;
    }
}

extern "C" void kernel_launch(void* const* d_in, const int* in_sizes, int n_in,
                              void* d_out, int out_size, void* d_ws, size_t ws_size,
                              hipStream_t stream) {
    (void)d_ws; (void)ws_size; (void)n_in; (void)out_size;
    const float* x = (const float*)d_in[0];
    float* out = (float*)d_out;
    int rows = in_sizes[0] / 2048;           // 32768
    feat_kernel<<<dim3(rows / 4), dim3(NTH), 0, stream>>>(x, out);
}